// Round 2
// baseline (375.101 us; speedup 1.0000x reference)
//
#include <hip/hip_runtime.h>
#include <math.h>

#define BN 8
#define SN 2048
#define DN 512
#define UN 512
#define MN (BN*SN)   // 16384

typedef _Float16 f16;
typedef _Float16 f16x8 __attribute__((ext_vector_type(8)));
typedef _Float16 f16x4 __attribute__((ext_vector_type(4)));
typedef float    f32x4 __attribute__((ext_vector_type(4)));

#define SCALE 0.044194173824159216f   // 1/sqrt(512)
#define LOG2E 1.4426950408889634f

__device__ __forceinline__ void gload_lds16(const f16* g, f16* l) {
  __builtin_amdgcn_global_load_lds(
      (const __attribute__((address_space(1))) unsigned int*)g,
      (__attribute__((address_space(3))) unsigned int*)l, 16, 0, 0);
}

// ---------------- fp32 -> fp16 convert of x ----------------
__global__ __launch_bounds__(256) void cvt_x_kernel(const float* __restrict__ x,
                                                    f16* __restrict__ x16) {
  int i = (blockIdx.x * 256 + threadIdx.x) * 4;
  float4 v = *(const float4*)(x + i);
  f16x4 o = { (f16)v.x, (f16)v.y, (f16)v.z, (f16)v.w };
  *(f16x4*)(x16 + i) = o;
}

// ------------- fp32 -> fp16 convert + transpose of W -------------
// Wt[widx][n][k] = W[k][n]
__global__ __launch_bounds__(256) void cvt_w_kernel(const float* __restrict__ Wq,
                                                    const float* __restrict__ Wk,
                                                    const float* __restrict__ Wv,
                                                    f16* __restrict__ Wt) {
  const float* W = blockIdx.y == 0 ? Wq : (blockIdx.y == 1 ? Wk : Wv);
  f16* o = Wt + (size_t)blockIdx.y * DN * UN;
  int t = blockIdx.x * 256 + threadIdx.x;   // 0..65535
  int r  = t >> 7;          // k row 0..511
  int c4 = (t & 127) * 4;   // n col
  float4 v = *(const float4*)(W + (size_t)r * UN + c4);
  o[(size_t)(c4 + 0) * DN + r] = (f16)v.x;
  o[(size_t)(c4 + 1) * DN + r] = (f16)v.y;
  o[(size_t)(c4 + 2) * DN + r] = (f16)v.z;
  o[(size_t)(c4 + 3) * DN + r] = (f16)v.w;
}

// ---------------- QKV projection GEMM ----------------
// C[M][N] = x[M][K] * W[K][N], via x row-major fp16 and W^T row-major fp16.
// 128x128 tile, BK=32, 256 threads (4 waves), wave -> 64x64 (4x4 frags).
// widx 0 -> Q (row-major), 1 -> K (row-major), 2 -> V stored transposed per batch.
__global__ __launch_bounds__(256) void qkv_gemm(const f16* __restrict__ x16,
                                                const f16* __restrict__ Wt,
                                                f16* __restrict__ Qh,
                                                f16* __restrict__ Kh,
                                                f16* __restrict__ Vt) {
  __shared__ __align__(16) f16 As[128 * 32];
  __shared__ __align__(16) f16 Bs[128 * 32];

  const int tid = threadIdx.x;
  const int w = tid >> 6, lane = tid & 63;
  const int l15 = lane & 15, lh = lane >> 4;
  const int m0 = blockIdx.x * 128;
  const int n0 = blockIdx.y * 128;
  const int widx = blockIdx.z;
  const f16* Wbase = Wt + (size_t)widx * DN * UN;

  const int wr = (w >> 1) * 64, wc = (w & 1) * 64;
  f32x4 acc[4][4] = {};

  for (int kk = 0; kk < 16; ++kk) {
    const int k0 = kk * 32;
#pragma unroll
    for (int q = 0; q < 2; ++q) {
      int j = q * 256 + tid;           // LDS chunk index (16B chunks)
      int r = j >> 2, cs = j & 3;
      int c = cs ^ ((r >> 1) & 3);     // inverse swizzle on the SOURCE
      f16* abase = &As[(q * 256 + w * 64) * 8];  // wave-uniform LDS base
      f16* bbase = &Bs[(q * 256 + w * 64) * 8];
      gload_lds16(x16 + (size_t)(m0 + r) * DN + k0 + c * 8, abase);
      gload_lds16(Wbase + (size_t)(n0 + r) * DN + k0 + c * 8, bbase);
    }
    __syncthreads();

    f16x8 a[4], bfr[4];
#pragma unroll
    for (int m = 0; m < 4; ++m) {
      int row = wr + m * 16 + l15;
      int ch = lh ^ ((row >> 1) & 3);  // swizzled read
      a[m] = *(const f16x8*)&As[row * 32 + ch * 8];
    }
#pragma unroll
    for (int n = 0; n < 4; ++n) {
      int row = wc + n * 16 + l15;
      int ch = lh ^ ((row >> 1) & 3);
      bfr[n] = *(const f16x8*)&Bs[row * 32 + ch * 8];
    }
#pragma unroll
    for (int m = 0; m < 4; ++m)
#pragma unroll
      for (int n = 0; n < 4; ++n)
        acc[m][n] = __builtin_amdgcn_mfma_f32_16x16x32_f16(a[m], bfr[n], acc[m][n], 0, 0, 0);
    __syncthreads();
  }

  // epilogue: C/D layout col=lane&15, row=(lane>>4)*4+j
  if (widx == 2) {
#pragma unroll
    for (int m = 0; m < 4; ++m) {
      int g = m0 + wr + m * 16 + lh * 4;   // + j rows
      int bb = g >> 11;
      int ss = g & 2047;
#pragma unroll
      for (int n = 0; n < 4; ++n) {
        int u = n0 + wc + n * 16 + l15;
        f16x4 pv = { (f16)acc[m][n][0], (f16)acc[m][n][1],
                     (f16)acc[m][n][2], (f16)acc[m][n][3] };
        *(f16x4*)(Vt + ((size_t)bb * UN + u) * SN + ss) = pv;  // V^T[b][u][s]
      }
    }
  } else {
    f16* O = (widx == 0) ? Qh : Kh;
#pragma unroll
    for (int m = 0; m < 4; ++m)
#pragma unroll
      for (int n = 0; n < 4; ++n)
#pragma unroll
        for (int j = 0; j < 4; ++j)
          O[(size_t)(m0 + wr + m * 16 + lh * 4 + j) * UN + (n0 + wc + n * 16 + l15)] =
              (f16)acc[m][n][j];
  }
}

// ---------------- fused flash attention ----------------
// grid (S/64, B), 512 threads (8 waves). Wave w: score rows rb*16 (rb=w>>1),
// score cols cw*32 (cw=w&1); PV output rows rb*16, cols cw*256.
__global__ __launch_bounds__(512) void attn_kernel(const f16* __restrict__ Qh,
                                                   const f16* __restrict__ Kh,
                                                   const f16* __restrict__ Vt,
                                                   float* __restrict__ out) {
  __shared__ __align__(16) f16 Ks[64 * DN];    // 64KB, chunk-swizzled
  __shared__ __align__(16) f16 Ps[64][72];     // padded: uniform-bank b128 reads
  __shared__ float redm[8][16];
  __shared__ float reds[8][16];

  const int tid = threadIdx.x;
  const int w = tid >> 6, lane = tid & 63;
  const int l15 = lane & 15, lh = lane >> 4;
  const int b = blockIdx.y;
  const int q0 = blockIdx.x * 64;
  const int rb = w >> 1;
  const int cw = w & 1;

  // Q fragments in registers: rows rb*16+l15, all 512 k
  const f16* Qbase = Qh + (size_t)(b * SN + q0 + rb * 16 + l15) * DN;
  f16x8 qf[16];
#pragma unroll
  for (int kk = 0; kk < 16; ++kk)
    qf[kk] = *(const f16x8*)(Qbase + kk * 32 + lh * 8);

  f32x4 acc[16] = {};
  float mj[4] = { -1e30f, -1e30f, -1e30f, -1e30f };
  float lj[4] = { 0.f, 0.f, 0.f, 0.f };

  const f16* Kbat = Kh + (size_t)b * SN * DN;
  const f16* Vbat = Vt + (size_t)b * UN * SN;

  for (int kv = 0; kv < SN; kv += 64) {
    // stage K tile [64][512] with XOR-swizzled source (chunk c stored at c^(r&7))
#pragma unroll
    for (int q = 0; q < 8; ++q) {
      int r = w * 8 + q;  // wave-uniform row
      gload_lds16(Kbat + (size_t)(kv + r) * DN + (lane ^ (r & 7)) * 8, &Ks[r * 512]);
    }
    __syncthreads();  // b1: K ready; also protects Ks/Ps vs prev iter readers

    // QK^T: 2 col-frags of 16, k = 512
    f32x4 sc[2] = {};
#pragma unroll
    for (int kk = 0; kk < 16; ++kk) {
#pragma unroll
      for (int fc = 0; fc < 2; ++fc) {
        int row = cw * 32 + fc * 16 + l15;
        int ch = (kk * 4 + lh) ^ (row & 7);
        f16x8 kf = *(const f16x8*)&Ks[row * 512 + ch * 8];
        sc[fc] = __builtin_amdgcn_mfma_f32_16x16x32_f16(qf[kk], kf, sc[fc], 0, 0, 0);
      }
    }

    // scale + per-row tile max (this wave's 32 cols)
    float tmax[4];
#pragma unroll
    for (int j = 0; j < 4; ++j) {
      sc[0][j] *= SCALE;
      sc[1][j] *= SCALE;
      tmax[j] = fmaxf(sc[0][j], sc[1][j]);
    }
#pragma unroll
    for (int off = 1; off < 16; off <<= 1)
#pragma unroll
      for (int j = 0; j < 4; ++j)
        tmax[j] = fmaxf(tmax[j], __shfl_xor(tmax[j], off, 64));
    if (l15 == 0) {
#pragma unroll
      for (int j = 0; j < 4; ++j) redm[w][lh * 4 + j] = tmax[j];
    }
    __syncthreads();  // b2: partial maxes visible

    float rs[4];
#pragma unroll
    for (int j = 0; j < 4; ++j) {
      float mnew = fmaxf(mj[j], fmaxf(tmax[j], redm[w ^ 1][lh * 4 + j]));
      rs[j] = exp2f((mj[j] - mnew) * LOG2E);
      mj[j] = mnew;
      lj[j] *= rs[j];
    }
#pragma unroll
    for (int n = 0; n < 16; ++n)
#pragma unroll
      for (int j = 0; j < 4; ++j) acc[n][j] *= rs[j];

    // P = exp(s - m), write to LDS, accumulate row sums
    float tsum[4] = { 0.f, 0.f, 0.f, 0.f };
#pragma unroll
    for (int fc = 0; fc < 2; ++fc)
#pragma unroll
      for (int j = 0; j < 4; ++j) {
        float p = exp2f((sc[fc][j] - mj[j]) * LOG2E);
        tsum[j] += p;
        Ps[rb * 16 + lh * 4 + j][cw * 32 + fc * 16 + l15] = (f16)p;
      }
#pragma unroll
    for (int off = 1; off < 16; off <<= 1)
#pragma unroll
      for (int j = 0; j < 4; ++j) tsum[j] += __shfl_xor(tsum[j], off, 64);
    if (l15 == 0) {
#pragma unroll
      for (int j = 0; j < 4; ++j) reds[w][lh * 4 + j] = tsum[j];
    }
    __syncthreads();  // b3: P + partial sums visible
#pragma unroll
    for (int j = 0; j < 4; ++j) lj[j] += tsum[j] + reds[w ^ 1][lh * 4 + j];

    // PV: O[rb*16 rows][cw*256 + n*16 cols] += P[.,64] * V[64, .]
    f16x8 pa[2];
#pragma unroll
    for (int ks = 0; ks < 2; ++ks)
      pa[ks] = *(const f16x8*)&Ps[rb * 16 + l15][ks * 32 + lh * 8];
#pragma unroll
    for (int n = 0; n < 16; ++n) {
      const f16* vp = Vbat + (size_t)(cw * 256 + n * 16 + l15) * SN + kv + lh * 8;
      f16x8 v0 = *(const f16x8*)vp;
      f16x8 v1 = *(const f16x8*)(vp + 32);
      acc[n] = __builtin_amdgcn_mfma_f32_16x16x32_f16(pa[0], v0, acc[n], 0, 0, 0);
      acc[n] = __builtin_amdgcn_mfma_f32_16x16x32_f16(pa[1], v1, acc[n], 0, 0, 0);
    }
  }

  // normalize + write fp32 output
#pragma unroll
  for (int j = 0; j < 4; ++j) {
    float inv = 1.0f / lj[j];
    float* orow = out + (size_t)(b * SN + q0 + rb * 16 + lh * 4 + j) * UN + cw * 256 + l15;
#pragma unroll
    for (int n = 0; n < 16; ++n) orow[n * 16] = acc[n][j] * inv;
  }
}

extern "C" void kernel_launch(void* const* d_in, const int* in_sizes, int n_in,
                              void* d_out, int out_size, void* d_ws, size_t ws_size,
                              hipStream_t stream) {
  const float* x  = (const float*)d_in[0];
  const float* Wq = (const float*)d_in[1];
  const float* Wk = (const float*)d_in[2];
  const float* Wv = (const float*)d_in[3];
  float* out = (float*)d_out;

  f16* x16 = (f16*)d_ws;                      // 16384*512 halves
  f16* Wt  = x16 + (size_t)MN * DN;           // 3*512*512
  f16* Qh  = Wt + (size_t)3 * DN * UN;        // 16384*512
  f16* Kh  = Qh + (size_t)MN * UN;            // 16384*512
  f16* Vt  = Kh + (size_t)MN * UN;            // 16384*512 (transposed per batch)
  // total ws use: 69,206,016 bytes

  cvt_x_kernel<<<dim3(MN * DN / 1024), 256, 0, stream>>>(x, x16);
  cvt_w_kernel<<<dim3(256, 3), 256, 0, stream>>>(Wq, Wk, Wv, Wt);
  qkv_gemm<<<dim3(128, 4, 3), 256, 0, stream>>>(x16, Wt, Qh, Kh, Vt);
  attn_kernel<<<dim3(32, 8), 512, 0, stream>>>(Qh, Kh, Vt, out);
}